// Round 11
// baseline (190.443 us; speedup 1.0000x reference)
//
#include <hip/hip_runtime.h>
#include <hip/hip_fp16.h>
#include <math.h>

// ---------------- problem constants ----------------
// x: (16, 2048, 64) f32  -> out: (16, 2048, 64, 5) f32
// scales = {1,27,76,167,336}; morlet int_psi, n=1024, [-8,8]
#define NB    16
#define T     2048
#define NC    64
#define NROWS (NB*NC)     // 1024
#define PADL2 2696        // left zero-pad (halves)
#define XSH_N 7440        // 2696 + 2048 + right pad
#define XSH_PAD 7568      // + prefetch-overrun slack (max B read ~7503)

// 32-diagonal Toeplitz W (for 32x32x16 MFMA), 16-halves chunk axis c16:
// Out[32A'+b'] = sum_k' W32[b'][k'-16*CLO16] * xsh[32A'+k'], k' = b'+i+posoff.
//   sl:      0      1      2      3      4
//   scale:   336    167    76     27     1
//   posoff:  7      1359   2087   2479   2687   (=2695-8s)
//   CLO16:   0      84     130    154    167
//   CHI16:   339    254    209    184    171
//   KS16:    5424   2720   1264   480    64     (row stride, halves)
//   WOFF32:  0      173568 260608 301056 316416 (total 318464 halves = 622KB)
//   outslot: 4      3      2      1      0
// alive segments (nested): [0,84)N1 [84,130)N2 [130,154)N3 [154,167)N4
//   [167,171)N5 [171,184)N4 [184,209)N3 [209,254)N2 [254,339)N1  (sum=622)

// ws layout (bytes):
//   0        : __half W32[318464]                  (622 KB, region 640 KB)
//   640 KB   : __half xT[1024][2048]               (4 MB)
//   640KB+4MB: __half outT2[16][128][64][5][16]    (20 MB)  [n][tb][c][s][tt]
#define WS_XT    655360u
#define WS_OUTT  4849664u

typedef _Float16 half8  __attribute__((ext_vector_type(8)));
typedef _Float16 half4v __attribute__((ext_vector_type(4)));
typedef float    f32x16 __attribute__((ext_vector_type(16)));

// ---------------- kernel 1: W32-build (blocks 0..31, one per diagonal b') ----------------
//                 + transpose (blocks 32..159)
// Values identical to the verified f64 pipeline except psi computed with f32
// expf/cosf (err ~1e-7 << fp16 quantization ~1e-3); prefix-sum and all index
// math (int64 floor of i/(s*step)) stay f64 — bit-identical j indices.
__global__ __launch_bounds__(1024) void cwt_prep(const float* __restrict__ x,
                                                 __half* __restrict__ xT,
                                                 __half* __restrict__ W) {
    __shared__ double ps[1024];
    __shared__ double sc[1024];
    __shared__ float  k32[1024];
    __shared__ float  tile4[4][64 * 65];
    const int tid = threadIdx.x;

    if (blockIdx.x < 32) {
        const int bb = blockIdx.x;                // diagonal b' in [0,32)
        constexpr int SCe[5]    = {336, 167, 76, 27, 1};
        constexpr int KS16[5]   = {5424, 2720, 1264, 480, 64};
        constexpr int WOFF32[5] = {0, 173568, 260608, 301056, 316416};
        constexpr int CLO16[5]  = {0, 84, 130, 154, 167};

        // zero-fill own rows only
        {
            const uint4 z = make_uint4(0u, 0u, 0u, 0u);
            #pragma unroll
            for (int sl = 0; sl < 5; ++sl) {
                uint4* z4 = (uint4*)(W + WOFF32[sl] + bb * KS16[sl]);
                const int n8 = KS16[sl] / 8;
                for (int i = tid; i < n8; i += 1024) z4[i] = z;
            }
        }

        const double delta = 16.0 / 1023.0;
        double t = (tid == 1023) ? 8.0 : (-8.0 + delta * (double)tid);
        {
            const float tf = (float)t;
            ps[tid] = (double)(expf(-0.5f * tf * tf) * cosf(5.0f * tf));
        }
        __syncthreads();   // also orders the zero-fill before the scatter below

        double* a = ps; double* b = sc;
        for (int off = 1; off < 1024; off <<= 1) {
            double v = a[tid];
            if (tid >= off) v += a[tid - off];
            b[tid] = v;
            __syncthreads();
            double* tmp = a; a = b; b = tmp;
        }
        const double step = ((-8.0 + delta) + 8.0);   // NOT exactly 16/1023
        k32[tid] = (float)(a[tid] * step);
        __syncthreads();

        for (int sl = 0; sl < 5; ++sl) {
            const int s = SCe[sl];
            const int L = 16 * s + 1;
            const double c = (double)s * step;
            const float sq = (float)sqrt((double)s);
            const int posoff = PADL2 - 8 * s - 1;
            const int kb0 = posoff - 16 * CLO16[sl];
            __half* wb = W + WOFF32[sl] + bb * KS16[sl];
            for (int i = tid; i <= L; i += 1024) {
                float g; bool wr = true;
                if (i == 0) {
                    g = sq * k32[0];
                } else if (i == L) {
                    long long jl = (long long)((double)(L - 1) / c);
                    if (jl > 1023) jl = 1023;
                    g = -sq * k32[jl];
                } else {
                    long long j1 = (long long)((double)i / c);
                    long long j0 = (long long)((double)(i - 1) / c);
                    if (j1 > 1023) j1 = 1023;
                    if (j0 > 1023) j0 = 1023;
                    wr = (j1 > j0);
                    g = sq * (k32[j1] - k32[j0]);
                }
                if (wr) {
                    wb[kb0 + i + bb] = __float2half(g);
                }
            }
        }
    } else {
        const int g    = tid >> 8;                // 0..3: tile within block
        const int t256 = tid & 255;
        const int ti   = (blockIdx.x - 32) * 4 + g;  // 0..511
        const int n    = ti >> 5;
        const int t0   = (ti & 31) << 6;
        float* tl = tile4[g];

        const float4* src = (const float4*)(x + ((size_t)(n * T + t0)) * NC);
        #pragma unroll
        for (int k = 0; k < 4; ++k) {
            float4 v = src[t256 + 256 * k];
            const int flat = (t256 + 256 * k) * 4;
            const int tt = flat >> 6, c = flat & 63;
            tl[tt * 65 + c + 0] = v.x;
            tl[tt * 65 + c + 1] = v.y;
            tl[tt * 65 + c + 2] = v.z;
            tl[tt * 65 + c + 3] = v.w;
        }
        __syncthreads();
        const int lane = t256 & 63, w4 = t256 >> 6;
        for (int cc = w4; cc < 64; cc += 4) {
            xT[((size_t)(n * 64 + cc)) * T + t0 + lane] = __float2half(tl[lane * 65 + cc]);
        }
    }
}

// ---------------- kernel 2: Toeplitz-block conv via 32x32x16 MFMA ----------------
// Per wave per 16k-window: 1 ds_read_b128 (B, shared across scales) + N A-loads
// + N MFMAs; one MFMA fills the wave's whole 32x32 (=1024 outputs) tile.
// vs 16x16x32/J=4: LDS reads halved (27->13.6us/CU), MFMA -12% (2382 ceiling).
// Round-9 lesson: per-CU pipes serialize, so cut the biggest term (LDS).
// Fragment layouts: A row=lane&31, k=8*(lane>>5)+q (row-major W32 rows);
// B col=lane&31 (A'-group), k=8*(lane>>5)+q (consecutive halves in xsh);
// D col=lane&31, row b'=(reg&3)+8*(reg>>2)+4*(lane>>5)  [m74/m101].
template<int N, int DEPTH>
__device__ __forceinline__ void conv_seg(int c0, int c1,
                                         const _Float16* __restrict__ xb,
                                         const _Float16* const (&ap)[5],
                                         f32x16 (&acc)[5]) {
    half8 A[DEPTH][N];
    half8 B[DEPTH];
    #pragma unroll
    for (int d = 0; d < DEPTH; ++d) {
        const int ko = (c0 + d) << 4;
        #pragma unroll
        for (int sl = 0; sl < N; ++sl) A[d][sl] = *(const half8*)(ap[sl] + ko);
        B[d] = *(const half8*)(xb + ko);
    }
    int c = c0;
    for (; c + DEPTH <= c1; c += DEPTH) {
        #pragma unroll
        for (int d = 0; d < DEPTH; ++d) {
            #pragma unroll
            for (int sl = 0; sl < N; ++sl)
                acc[sl] = __builtin_amdgcn_mfma_f32_32x32x16_f16(A[d][sl], B[d], acc[sl], 0, 0, 0);
            const int ko = (c + DEPTH + d) << 4;   // prefetch (unclamped, memory-safe:
            #pragma unroll                         // stays inside xsh pad / W region)
            for (int sl = 0; sl < N; ++sl) A[d][sl] = *(const half8*)(ap[sl] + ko);
            B[d] = *(const half8*)(xb + ko);
        }
    }
    #pragma unroll
    for (int d = 0; d < DEPTH; ++d) {
        if (d < c1 - c) {
            #pragma unroll
            for (int sl = 0; sl < N; ++sl)
                acc[sl] = __builtin_amdgcn_mfma_f32_32x32x16_f16(A[d][sl], B[d], acc[sl], 0, 0, 0);
        }
    }
}

__global__ __launch_bounds__(128, 2) void cwt_conv_mfma(const __half* __restrict__ xT,
                                                        const __half* __restrict__ Wg,
                                                        __half* __restrict__ outT) {
    constexpr int KS16[5]   = {5424, 2720, 1264, 480, 64};
    constexpr int WOFF32[5] = {0, 173568, 260608, 301056, 316416};
    constexpr int CLO16[5]  = {0, 84, 130, 154, 167};
    constexpr int OS[5]     = {4, 3, 2, 1, 0};

    __shared__ _Float16 xsh[XSH_PAD];             // 15136 B (incl. overrun pad)
    __shared__ _Float16 ostage[2048];             // 4096 B (1024/wave)
    const int tid  = threadIdx.x;
    const int row  = blockIdx.x;
    const int nidx = row >> 6;                    // batch n
    const int cidx = row & 63;                    // channel c
    const int lane = tid & 63;
    const int w    = tid >> 6;                    // wave 0/1: A'-groups [32w, 32w+32)
    const int col  = lane & 31;                   // A-frag: W32 row b'; B/D: col (A'-group)
    const int kh   = lane >> 5;                   // k-half within 16k window

    // ---- stage padded signal row (fp16), 128 threads ----
    {
        uint4* x4 = (uint4*)xsh;
        const uint4 z = make_uint4(0u, 0u, 0u, 0u);
        for (int i = tid; i < XSH_N / 8; i += 128)
            if (i < PADL2 / 8 || i >= (PADL2 + T) / 8) x4[i] = z;
        const uint4* src = (const uint4*)(xT + (size_t)row * T);
        x4[PADL2 / 8 + tid] = src[tid];
        x4[PADL2 / 8 + 128 + tid] = src[128 + tid];
    }
    __syncthreads();

    // per-lane operand bases
    const _Float16* xb = xsh + 32 * (32 * w + col) + 8 * kh;
    const _Float16* ap[5];
    #pragma unroll
    for (int sl = 0; sl < 5; ++sl)
        ap[sl] = (const _Float16*)Wg + WOFF32[sl] + col * KS16[sl] + 8 * kh
                 - 16 * CLO16[sl];

    f32x16 acc[5];
    #pragma unroll
    for (int sl = 0; sl < 5; ++sl)
        #pragma unroll
        for (int r = 0; r < 16; ++r) acc[sl][r] = 0.f;

    // nested alive segments over the 16k-chunk axis
    conv_seg<1,4>(  0,  84, xb, ap, acc);
    conv_seg<2,3>( 84, 130, xb, ap, acc);
    conv_seg<3,2>(130, 154, xb, ap, acc);
    conv_seg<4,2>(154, 167, xb, ap, acc);
    conv_seg<5,1>(167, 171, xb, ap, acc);
    conv_seg<4,2>(171, 184, xb, ap, acc);
    conv_seg<3,2>(184, 209, xb, ap, acc);
    conv_seg<2,3>(209, 254, xb, ap, acc);
    conv_seg<1,4>(254, 339, xb, ap, acc);

    // ---- epilogue: t = 1024w + 32*col + b'; stage 32x32 D, then coalesced out ----
    // outT2 [n][tb][c][s][16]: lane l covers tb = 64w + l, tt 0..15.
    _Float16* os = ostage + 1024 * w;             // wave-local, no barrier needed
    #pragma unroll
    for (int sl = 0; sl < 5; ++sl) {
        #pragma unroll
        for (int rq = 0; rq < 4; ++rq) {          // b' = (r&3) + 8*rq + 4*kh
            half4v hv;
            #pragma unroll
            for (int r = 0; r < 4; ++r) hv[r] = (_Float16)acc[sl][4 * rq + r];
            *(half4v*)(os + 32 * col + 8 * rq + 4 * kh) = hv;
        }
        half8 o0 = *(const half8*)(os + 16 * lane);
        half8 o1 = *(const half8*)(os + 16 * lane + 8);
        __half* ob = outT + ((size_t)(((nidx * 128 + 64 * w + lane) * 64 + cidx) * 5 + OS[sl])) * 16;
        *(half8*)(ob)     = o0;
        *(half8*)(ob + 8) = o1;
    }
}

// ---------------- kernel 3: outT2[n][tb][c][s][16] -> out[n][t][c][s] ----------------
__global__ __launch_bounds__(256) void cwt_fix(const __half* __restrict__ outT,
                                               float* __restrict__ out) {
    __shared__ float tile[16 * 320];              // [tt][c*5+s]
    const int b  = blockIdx.x;                    // 0..2047
    const int n  = b >> 7;
    const int tb = b & 127;
    const int tid = threadIdx.x;

    const uint4* src = (const uint4*)(outT + (size_t)(n * 128 + tb) * 5120);
    for (int i = tid; i < 640; i += 256) {
        uint4 v = src[i];                         // 8 halves: (c,s) fixed, tt0..tt0+7
        const __half* h = (const __half*)&v;
        const int h0  = i * 8;
        const int sg  = h0 >> 4;                  // c*5+s
        const int tt0 = h0 & 15;                  // 0 or 8
        #pragma unroll
        for (int k = 0; k < 8; ++k) tile[(tt0 + k) * 320 + sg] = __half2float(h[k]);
    }
    __syncthreads();
    float4* dst = (float4*)(out + (size_t)(n * 2048 + tb * 16) * 320);
    const float4* tl = (const float4*)tile;
    for (int k = tid; k < 1280; k += 256) dst[k] = tl[k];
}

// ---------------- launch ----------------
extern "C" void kernel_launch(void* const* d_in, const int* in_sizes, int n_in,
                              void* d_out, int out_size, void* d_ws, size_t ws_size,
                              hipStream_t stream) {
    const float* x = (const float*)d_in[0];
    float* out = (float*)d_out;
    char* ws = (char*)d_ws;

    __half* W    = (__half*)ws;
    __half* xT   = (__half*)(ws + WS_XT);
    __half* outT = (__half*)(ws + WS_OUTT);

    cwt_prep<<<160, 1024, 0, stream>>>(x, xT, W);
    cwt_conv_mfma<<<NROWS, 128, 0, stream>>>(xT, W, outT);
    cwt_fix<<<2048, 256, 0, stream>>>(outT, out);
}

// Round 12
// 144.847 us; speedup vs baseline: 1.3148x; 1.3148x over previous
//
#include <hip/hip_runtime.h>
#include <hip/hip_fp16.h>
#include <math.h>

// ---------------- problem constants ----------------
// x: (16, 2048, 64) f32  -> out: (16, 2048, 64, 5) f32
// scales = {1,27,76,167,336}; morlet int_psi, n=1024, [-8,8]
#define NB    16
#define T     2048
#define NC    64
#define NROWS (NB*NC)     // 1024
#define PADL2 2696        // left zero-pad (halves)
#define XSH_N 7440        // 2696 + 2048 + right pad
#define XSH_PAD 7568      // + prefetch-overrun slack (max B read ~7528)

// 32-diagonal Toeplitz W (for 32x32x16 MFMA), 16-halves chunk axis c16:
// Out[32A'+b'] = sum_k' W32[b'][k'-16*CLO16] * xsh[32A'+k'], k' = b'+i+posoff.
//   sl:      0      1      2      3      4
//   scale:   336    167    76     27     1
//   posoff:  7      1359   2087   2479   2687   (=2695-8s)
//   CLO16:   0      84     130    154    167
//   CHI16:   339    254    209    184    171
//   KS16:    5424   2720   1264   480    64     (row stride, halves)
//   WOFF32:  0      173568 260608 301056 316416 (total 318464 halves = 622KB)
//   outslot: 4      3      2      1      0
// alive segments (nested): [0,84)N1 [84,130)N2 [130,154)N3 [154,167)N4
//   [167,171)N5 [171,184)N4 [184,209)N3 [209,254)N2 [254,339)N1  (sum=622)
// Layout VERIFIED on HW (round 11, absmax 0.0625).

// ws layout (bytes):
//   0        : __half W32[318464]                  (622 KB, region 640 KB)
//   640 KB   : __half xT[1024][2048]               (4 MB)
//   640KB+4MB: __half outT2[16][128][64][5][16]    (20 MB)  [n][tb][c][s][tt]
#define WS_XT    655360u
#define WS_OUTT  4849664u

typedef _Float16 half8  __attribute__((ext_vector_type(8)));
typedef _Float16 half4v __attribute__((ext_vector_type(4)));
typedef float    f32x16 __attribute__((ext_vector_type(16)));

// ---------------- kernel 1: W32-build (blocks 0..31, one per diagonal b') ----------------
//                 + transpose (blocks 32..159)   [verified round 11]
__global__ __launch_bounds__(1024) void cwt_prep(const float* __restrict__ x,
                                                 __half* __restrict__ xT,
                                                 __half* __restrict__ W) {
    __shared__ double ps[1024];
    __shared__ double sc[1024];
    __shared__ float  k32[1024];
    __shared__ float  tile4[4][64 * 65];
    const int tid = threadIdx.x;

    if (blockIdx.x < 32) {
        const int bb = blockIdx.x;                // diagonal b' in [0,32)
        constexpr int SCe[5]    = {336, 167, 76, 27, 1};
        constexpr int KS16[5]   = {5424, 2720, 1264, 480, 64};
        constexpr int WOFF32[5] = {0, 173568, 260608, 301056, 316416};
        constexpr int CLO16[5]  = {0, 84, 130, 154, 167};

        // zero-fill own rows only
        {
            const uint4 z = make_uint4(0u, 0u, 0u, 0u);
            #pragma unroll
            for (int sl = 0; sl < 5; ++sl) {
                uint4* z4 = (uint4*)(W + WOFF32[sl] + bb * KS16[sl]);
                const int n8 = KS16[sl] / 8;
                for (int i = tid; i < n8; i += 1024) z4[i] = z;
            }
        }

        const double delta = 16.0 / 1023.0;
        double t = (tid == 1023) ? 8.0 : (-8.0 + delta * (double)tid);
        {
            const float tf = (float)t;
            ps[tid] = (double)(expf(-0.5f * tf * tf) * cosf(5.0f * tf));
        }
        __syncthreads();   // also orders the zero-fill before the scatter below

        double* a = ps; double* b = sc;
        for (int off = 1; off < 1024; off <<= 1) {
            double v = a[tid];
            if (tid >= off) v += a[tid - off];
            b[tid] = v;
            __syncthreads();
            double* tmp = a; a = b; b = tmp;
        }
        const double step = ((-8.0 + delta) + 8.0);   // NOT exactly 16/1023
        k32[tid] = (float)(a[tid] * step);
        __syncthreads();

        for (int sl = 0; sl < 5; ++sl) {
            const int s = SCe[sl];
            const int L = 16 * s + 1;
            const double c = (double)s * step;
            const float sq = (float)sqrt((double)s);
            const int posoff = PADL2 - 8 * s - 1;
            const int kb0 = posoff - 16 * CLO16[sl];
            __half* wb = W + WOFF32[sl] + bb * KS16[sl];
            for (int i = tid; i <= L; i += 1024) {
                float g; bool wr = true;
                if (i == 0) {
                    g = sq * k32[0];
                } else if (i == L) {
                    long long jl = (long long)((double)(L - 1) / c);
                    if (jl > 1023) jl = 1023;
                    g = -sq * k32[jl];
                } else {
                    long long j1 = (long long)((double)i / c);
                    long long j0 = (long long)((double)(i - 1) / c);
                    if (j1 > 1023) j1 = 1023;
                    if (j0 > 1023) j0 = 1023;
                    wr = (j1 > j0);
                    g = sq * (k32[j1] - k32[j0]);
                }
                if (wr) {
                    wb[kb0 + i + bb] = __float2half(g);
                }
            }
        }
    } else {
        const int g    = tid >> 8;                // 0..3: tile within block
        const int t256 = tid & 255;
        const int ti   = (blockIdx.x - 32) * 4 + g;  // 0..511
        const int n    = ti >> 5;
        const int t0   = (ti & 31) << 6;
        float* tl = tile4[g];

        const float4* src = (const float4*)(x + ((size_t)(n * T + t0)) * NC);
        #pragma unroll
        for (int k = 0; k < 4; ++k) {
            float4 v = src[t256 + 256 * k];
            const int flat = (t256 + 256 * k) * 4;
            const int tt = flat >> 6, c = flat & 63;
            tl[tt * 65 + c + 0] = v.x;
            tl[tt * 65 + c + 1] = v.y;
            tl[tt * 65 + c + 2] = v.z;
            tl[tt * 65 + c + 3] = v.w;
        }
        __syncthreads();
        const int lane = t256 & 63, w4 = t256 >> 6;
        for (int cc = w4; cc < 64; cc += 4) {
            xT[((size_t)(n * 64 + cc)) * T + t0 + lane] = __float2half(tl[lane * 65 + cc]);
        }
    }
}

// ---------------- kernel 2: 32x32x16 MFMA conv, 2 ROWS PER WAVE ----------------
// Round-11 lesson: VMEM wave-instr per MFMA is the controlling variable
// (J=4 -> 66us, J=2/J=1 -> 111us). W (A operand) is row-independent, so each
// A-load now feeds 2 MFMAs (one per signal row) -> per-CU VMEM halved vs
// round 11 while keeping the halved ds_read count of 32x32.
// Block = 2 waves (col halves) x 2 rows staged; grid = 512 row-pairs.
// Fragment layout VERIFIED round 11 (absmax 0.0625).
template<int N, int DEPTH>
__device__ __forceinline__ void conv_seg(int c0, int c1,
                                         const _Float16* __restrict__ xb0,
                                         const _Float16* __restrict__ xb1,
                                         const _Float16* const (&ap)[5],
                                         f32x16 (&acc)[5][2]) {
    half8 A[DEPTH][N];
    half8 B0[DEPTH], B1[DEPTH];
    #pragma unroll
    for (int d = 0; d < DEPTH; ++d) {
        const int ko = (c0 + d) << 4;
        #pragma unroll
        for (int sl = 0; sl < N; ++sl) A[d][sl] = *(const half8*)(ap[sl] + ko);
        B0[d] = *(const half8*)(xb0 + ko);
        B1[d] = *(const half8*)(xb1 + ko);
    }
    int c = c0;
    for (; c + DEPTH <= c1; c += DEPTH) {
        #pragma unroll
        for (int d = 0; d < DEPTH; ++d) {
            #pragma unroll
            for (int sl = 0; sl < N; ++sl) {
                acc[sl][0] = __builtin_amdgcn_mfma_f32_32x32x16_f16(A[d][sl], B0[d], acc[sl][0], 0, 0, 0);
                acc[sl][1] = __builtin_amdgcn_mfma_f32_32x32x16_f16(A[d][sl], B1[d], acc[sl][1], 0, 0, 0);
            }
            const int ko = (c + DEPTH + d) << 4;   // prefetch (unclamped, memory-safe:
            #pragma unroll                         // stays inside W region / xsh+ostage)
            for (int sl = 0; sl < N; ++sl) A[d][sl] = *(const half8*)(ap[sl] + ko);
            B0[d] = *(const half8*)(xb0 + ko);
            B1[d] = *(const half8*)(xb1 + ko);
        }
    }
    #pragma unroll
    for (int d = 0; d < DEPTH; ++d) {
        if (d < c1 - c) {
            #pragma unroll
            for (int sl = 0; sl < N; ++sl) {
                acc[sl][0] = __builtin_amdgcn_mfma_f32_32x32x16_f16(A[d][sl], B0[d], acc[sl][0], 0, 0, 0);
                acc[sl][1] = __builtin_amdgcn_mfma_f32_32x32x16_f16(A[d][sl], B1[d], acc[sl][1], 0, 0, 0);
            }
        }
    }
}

__global__ __launch_bounds__(128, 1) void cwt_conv_mfma(const __half* __restrict__ xT,
                                                        const __half* __restrict__ Wg,
                                                        __half* __restrict__ outT) {
    constexpr int KS16[5]   = {5424, 2720, 1264, 480, 64};
    constexpr int WOFF32[5] = {0, 173568, 260608, 301056, 316416};
    constexpr int CLO16[5]  = {0, 84, 130, 154, 167};
    constexpr int OS[5]     = {4, 3, 2, 1, 0};

    __shared__ _Float16 xsh[2][XSH_PAD];          // 30272 B (2 rows + overrun pad)
    __shared__ _Float16 ostage[2048];             // 4096 B (1024/wave)
    const int tid  = threadIdx.x;
    const int rp   = blockIdx.x;                  // row pair: rows 2rp, 2rp+1
    const int lane = tid & 63;
    const int w    = tid >> 6;                    // wave 0/1: A'-groups [32w, 32w+32)
    const int col  = lane & 31;                   // A-frag: W32 row b'; B/D: col (A'-group)
    const int kh   = lane >> 5;                   // k-half within 16k window

    // ---- stage both padded signal rows (fp16), 128 threads ----
    {
        const uint4 z = make_uint4(0u, 0u, 0u, 0u);
        #pragma unroll
        for (int rr = 0; rr < 2; ++rr) {
            uint4* x4 = (uint4*)xsh[rr];
            for (int i = tid; i < XSH_N / 8; i += 128)
                if (i < PADL2 / 8 || i >= (PADL2 + T) / 8) x4[i] = z;
            const uint4* src = (const uint4*)(xT + (size_t)(2 * rp + rr) * T);
            x4[PADL2 / 8 + tid] = src[tid];
            x4[PADL2 / 8 + 128 + tid] = src[128 + tid];
        }
    }
    __syncthreads();

    // per-lane operand bases
    const _Float16* xb0 = xsh[0] + 32 * (32 * w + col) + 8 * kh;
    const _Float16* xb1 = xsh[1] + 32 * (32 * w + col) + 8 * kh;
    const _Float16* ap[5];
    #pragma unroll
    for (int sl = 0; sl < 5; ++sl)
        ap[sl] = (const _Float16*)Wg + WOFF32[sl] + col * KS16[sl] + 8 * kh
                 - 16 * CLO16[sl];

    f32x16 acc[5][2];
    #pragma unroll
    for (int sl = 0; sl < 5; ++sl)
        #pragma unroll
        for (int rr = 0; rr < 2; ++rr)
            #pragma unroll
            for (int r = 0; r < 16; ++r) acc[sl][rr][r] = 0.f;

    // nested alive segments over the 16k-chunk axis
    conv_seg<1,4>(  0,  84, xb0, xb1, ap, acc);
    conv_seg<2,3>( 84, 130, xb0, xb1, ap, acc);
    conv_seg<3,2>(130, 154, xb0, xb1, ap, acc);
    conv_seg<4,2>(154, 167, xb0, xb1, ap, acc);
    conv_seg<5,1>(167, 171, xb0, xb1, ap, acc);
    conv_seg<4,2>(171, 184, xb0, xb1, ap, acc);
    conv_seg<3,2>(184, 209, xb0, xb1, ap, acc);
    conv_seg<2,3>(209, 254, xb0, xb1, ap, acc);
    conv_seg<1,4>(254, 339, xb0, xb1, ap, acc);

    // ---- epilogue per row: t = 1024w + 32*col + b'; stage 32x32 D, coalesced out ----
    // outT2 [n][tb][c][s][16]: lane l covers tb = 64w + l, tt 0..15.  [verified r11]
    _Float16* os = ostage + 1024 * w;             // wave-local, in-order LDS per wave
    #pragma unroll
    for (int rr = 0; rr < 2; ++rr) {
        const int row  = 2 * rp + rr;
        const int nidx = row >> 6;
        const int cidx = row & 63;
        #pragma unroll
        for (int sl = 0; sl < 5; ++sl) {
            #pragma unroll
            for (int rq = 0; rq < 4; ++rq) {      // b' = (r&3) + 8*rq + 4*kh
                half4v hv;
                #pragma unroll
                for (int r = 0; r < 4; ++r) hv[r] = (_Float16)acc[sl][rr][4 * rq + r];
                *(half4v*)(os + 32 * col + 8 * rq + 4 * kh) = hv;
            }
            half8 o0 = *(const half8*)(os + 16 * lane);
            half8 o1 = *(const half8*)(os + 16 * lane + 8);
            __half* ob = outT + ((size_t)(((nidx * 128 + 64 * w + lane) * 64 + cidx) * 5 + OS[sl])) * 16;
            *(half8*)(ob)     = o0;
            *(half8*)(ob + 8) = o1;
        }
    }
}

// ---------------- kernel 3: outT2[n][tb][c][s][16] -> out[n][t][c][s] ----------------
__global__ __launch_bounds__(256) void cwt_fix(const __half* __restrict__ outT,
                                               float* __restrict__ out) {
    __shared__ float tile[16 * 320];              // [tt][c*5+s]
    const int b  = blockIdx.x;                    // 0..2047
    const int n  = b >> 7;
    const int tb = b & 127;
    const int tid = threadIdx.x;

    const uint4* src = (const uint4*)(outT + (size_t)(n * 128 + tb) * 5120);
    for (int i = tid; i < 640; i += 256) {
        uint4 v = src[i];                         // 8 halves: (c,s) fixed, tt0..tt0+7
        const __half* h = (const __half*)&v;
        const int h0  = i * 8;
        const int sg  = h0 >> 4;                  // c*5+s
        const int tt0 = h0 & 15;                  // 0 or 8
        #pragma unroll
        for (int k = 0; k < 8; ++k) tile[(tt0 + k) * 320 + sg] = __half2float(h[k]);
    }
    __syncthreads();
    float4* dst = (float4*)(out + (size_t)(n * 2048 + tb * 16) * 320);
    const float4* tl = (const float4*)tile;
    for (int k = tid; k < 1280; k += 256) dst[k] = tl[k];
}

// ---------------- launch ----------------
extern "C" void kernel_launch(void* const* d_in, const int* in_sizes, int n_in,
                              void* d_out, int out_size, void* d_ws, size_t ws_size,
                              hipStream_t stream) {
    const float* x = (const float*)d_in[0];
    float* out = (float*)d_out;
    char* ws = (char*)d_ws;

    __half* W    = (__half*)ws;
    __half* xT   = (__half*)(ws + WS_XT);
    __half* outT = (__half*)(ws + WS_OUTT);

    cwt_prep<<<160, 1024, 0, stream>>>(x, xT, W);
    cwt_conv_mfma<<<NROWS / 2, 128, 0, stream>>>(xT, W, outT);
    cwt_fix<<<2048, 256, 0, stream>>>(outT, out);
}